// Round 2
// baseline (671.298 us; speedup 1.0000x reference)
//
#include <hip/hip_runtime.h>
#include <hip/hip_bf16.h>

// Problem constants
constexpr int Bn = 8, Sn = 2048, En = 512, Hn = 4, Dn = 128;
constexpr int BHn = Bn * Hn;          // 32
constexpr int Mqkv = Bn * Sn;         // 16384

typedef __attribute__((ext_vector_type(8))) short short8;
typedef __attribute__((ext_vector_type(4))) float f32x4;

__device__ __forceinline__ unsigned short f2bf(float f) {
  unsigned int u = __builtin_bit_cast(unsigned int, f);
  u += 0x7FFF + ((u >> 16) & 1);   // round-to-nearest-even
  return (unsigned short)(u >> 16);
}

// ---------------------------------------------------------------------------
// K1: QKV projection.  out[z][bh][s][d] (bf16) = x[b,s,:]@W[:,e] + bias[s]
// grid (M/128, N/128=4, 3); block 256 (4 waves, 2x2 of the 128x128 tile)
// ---------------------------------------------------------------------------
__global__ __launch_bounds__(256) void qkv_kernel(
    const float* __restrict__ x, const float* __restrict__ Wq,
    const float* __restrict__ Wk, const float* __restrict__ Wv,
    const float* __restrict__ bq, const float* __restrict__ bk,
    const float* __restrict__ bv, unsigned short* __restrict__ qkv) {
  const int z = blockIdx.z;
  const float* W = (z == 0) ? Wq : (z == 1 ? Wk : Wv);
  const float* bias = (z == 0) ? bq : (z == 1 ? bk : bv);
  unsigned short* out = qkv + (size_t)z * BHn * Sn * Dn;

  __shared__ unsigned short As[128][40];   // [m][k], pad to 40
  __shared__ unsigned short BsT[128][40];  // [n][k] (W transposed)

  const int t = threadIdx.x;
  const int l = t & 63, w = t >> 6;
  const int wm = w >> 1, wn = w & 1;
  const int m0 = blockIdx.x * 128, n0 = blockIdx.y * 128;

  f32x4 acc[4][4] = {};

  for (int k0 = 0; k0 < En; k0 += 32) {
    __syncthreads();
#pragma unroll
    for (int i = 0; i < 4; ++i) {
      int idx = t + i * 256;
      int row = idx >> 3, c4 = (idx & 7) * 4;
      float4 v = *reinterpret_cast<const float4*>(&x[(size_t)(m0 + row) * En + k0 + c4]);
      ushort4 p;
      p.x = f2bf(v.x); p.y = f2bf(v.y); p.z = f2bf(v.z); p.w = f2bf(v.w);
      *reinterpret_cast<ushort4*>(&As[row][c4]) = p;
    }
#pragma unroll
    for (int i = 0; i < 4; ++i) {
      int idx = t + i * 256;
      int kk = idx >> 5, c4 = (idx & 31) * 4;
      float4 v = *reinterpret_cast<const float4*>(&W[(size_t)(k0 + kk) * En + n0 + c4]);
      BsT[c4 + 0][kk] = f2bf(v.x);
      BsT[c4 + 1][kk] = f2bf(v.y);
      BsT[c4 + 2][kk] = f2bf(v.z);
      BsT[c4 + 3][kk] = f2bf(v.w);
    }
    __syncthreads();

    const int koff = (l >> 4) * 8;
    short8 a[4], bfr[4];
#pragma unroll
    for (int m = 0; m < 4; ++m)
      a[m] = *reinterpret_cast<const short8*>(&As[wm * 64 + m * 16 + (l & 15)][koff]);
#pragma unroll
    for (int n = 0; n < 4; ++n)
      bfr[n] = *reinterpret_cast<const short8*>(&BsT[wn * 64 + n * 16 + (l & 15)][koff]);
#pragma unroll
    for (int m = 0; m < 4; ++m)
#pragma unroll
      for (int n = 0; n < 4; ++n)
        acc[m][n] = __builtin_amdgcn_mfma_f32_16x16x32_bf16(a[m], bfr[n], acc[m][n], 0, 0, 0);
  }

#pragma unroll
  for (int m = 0; m < 4; ++m)
#pragma unroll
    for (int n = 0; n < 4; ++n)
#pragma unroll
      for (int j = 0; j < 4; ++j) {
        int row = m0 + wm * 64 + m * 16 + (l >> 4) * 4 + j;
        int col = n0 + wn * 64 + n * 16 + (l & 15);
        int s = row & (Sn - 1);
        float v = acc[m][n][j] + bias[s];
        int b = row >> 11;           // row / 2048
        int h = col >> 7, d = col & 127;
        out[(size_t)((b * Hn + h) * Sn + s) * Dn + d] = f2bf(v);
      }
}

// ---------------------------------------------------------------------------
// K2: fused scores+softmax+mask+attn-write+PV.
// One block = 64 query rows of one (b,h).  grid (Sn/64=32, BHn=32), 256 thr.
// 4 waves split the 128-col tile 1x4 (each wave: 64 rows x 32 cols).
// Sweep 1: row sums of exp(scale*q.k) (no max subtraction: |score| <= ~2).
// Sweep 2: recompute scores, p = exp*invl*Wepi -> write attn f32 once,
//          bf16 P to LDS, MFMA-accumulate PV; epilogue effect = pv + bo.
// ---------------------------------------------------------------------------
__global__ __launch_bounds__(256, 2) void fused_attn_kernel(
    const unsigned short* __restrict__ qkv, const float* __restrict__ Wepi,
    const float* __restrict__ bo, float* __restrict__ attn,
    float* __restrict__ effect) {
  const int bh = blockIdx.y;
  const int s0 = blockIdx.x * 64;
  const unsigned short* q = qkv + (size_t)bh * Sn * Dn;
  const unsigned short* kptr = qkv + (size_t)(BHn + bh) * Sn * Dn;
  const unsigned short* vptr = qkv + (size_t)(2 * BHn + bh) * Sn * Dn;

  __shared__ unsigned short Qs[64][136];
  __shared__ unsigned short KVs[128][136];   // K tile, then V tile (swizzled)
  __shared__ unsigned short Ps[64][136];
  __shared__ float wpart[4][64];
  __shared__ float invl[64];

  const int t = threadIdx.x, l = t & 63, w = t >> 6;
  const int g = l >> 4, i = l & 15;
  const float scale = 0.022097086912079608f;  // 1/sqrt(2048)

  // stage Q tile (resident for whole kernel)
#pragma unroll
  for (int it = 0; it < 4; ++it) {
    int idx = t + it * 256;
    int row = idx >> 4, c8 = (idx & 15) * 8;
    *reinterpret_cast<short8*>(&Qs[row][c8]) =
        *reinterpret_cast<const short8*>(&q[(size_t)(s0 + row) * Dn + c8]);
  }

  float rs[4][4];
#pragma unroll
  for (int mf = 0; mf < 4; ++mf)
#pragma unroll
    for (int j = 0; j < 4; ++j) rs[mf][j] = 0.f;

  // ---------------- sweep 1: exp-sums ----------------
  for (int kt = 0; kt < 16; ++kt) {
    const int t0 = kt * 128;
    __syncthreads();
#pragma unroll
    for (int it = 0; it < 8; ++it) {
      int idx = t + it * 256;
      int row = idx >> 4, c8 = (idx & 15) * 8;
      *reinterpret_cast<short8*>(&KVs[row][c8]) =
          *reinterpret_cast<const short8*>(&kptr[(size_t)(t0 + row) * Dn + c8]);
    }
    __syncthreads();

    f32x4 acc[4][2] = {};
#pragma unroll
    for (int ks = 0; ks < 4; ++ks) {
      const int koff = ks * 32 + g * 8;
      short8 a[4], b[2];
#pragma unroll
      for (int mf = 0; mf < 4; ++mf)
        a[mf] = *reinterpret_cast<const short8*>(&Qs[mf * 16 + i][koff]);
#pragma unroll
      for (int nf = 0; nf < 2; ++nf)
        b[nf] = *reinterpret_cast<const short8*>(&KVs[w * 32 + nf * 16 + i][koff]);
#pragma unroll
      for (int mf = 0; mf < 4; ++mf)
#pragma unroll
        for (int nf = 0; nf < 2; ++nf)
          acc[mf][nf] = __builtin_amdgcn_mfma_f32_16x16x32_bf16(a[mf], b[nf], acc[mf][nf], 0, 0, 0);
    }
#pragma unroll
    for (int mf = 0; mf < 4; ++mf)
#pragma unroll
      for (int j = 0; j < 4; ++j) {
        float s = __expf(acc[mf][0][j] * scale) + __expf(acc[mf][1][j] * scale);
        s += __shfl_xor(s, 1); s += __shfl_xor(s, 2);
        s += __shfl_xor(s, 4); s += __shfl_xor(s, 8);
        rs[mf][j] += s;   // row sum over this wave's 32 cols, all 16 lanes agree
      }
  }
  if (i == 0) {
#pragma unroll
    for (int mf = 0; mf < 4; ++mf)
#pragma unroll
      for (int j = 0; j < 4; ++j)
        wpart[w][mf * 16 + g * 4 + j] = rs[mf][j];
  }
  __syncthreads();
  if (t < 64) invl[t] = 1.0f / (wpart[0][t] + wpart[1][t] + wpart[2][t] + wpart[3][t]);

  // ---------------- sweep 2: recompute, write attn, PV ----------------
  f32x4 pv[4][2] = {};
  float* attn_bh = attn + (size_t)bh * Sn * Sn;
  for (int kt = 0; kt < 16; ++kt) {
    const int t0 = kt * 128;
    __syncthreads();  // invl visible (kt=0); prior tile's KVs/Ps reads done
#pragma unroll
    for (int it = 0; it < 8; ++it) {
      int idx = t + it * 256;
      int row = idx >> 4, c8 = (idx & 15) * 8;
      *reinterpret_cast<short8*>(&KVs[row][c8]) =
          *reinterpret_cast<const short8*>(&kptr[(size_t)(t0 + row) * Dn + c8]);
    }
    __syncthreads();

    f32x4 acc[4][2] = {};
#pragma unroll
    for (int ks = 0; ks < 4; ++ks) {
      const int koff = ks * 32 + g * 8;
      short8 a[4], b[2];
#pragma unroll
      for (int mf = 0; mf < 4; ++mf)
        a[mf] = *reinterpret_cast<const short8*>(&Qs[mf * 16 + i][koff]);
#pragma unroll
      for (int nf = 0; nf < 2; ++nf)
        b[nf] = *reinterpret_cast<const short8*>(&KVs[w * 32 + nf * 16 + i][koff]);
#pragma unroll
      for (int mf = 0; mf < 4; ++mf)
#pragma unroll
        for (int nf = 0; nf < 2; ++nf)
          acc[mf][nf] = __builtin_amdgcn_mfma_f32_16x16x32_bf16(a[mf], b[nf], acc[mf][nf], 0, 0, 0);
    }
    __syncthreads();  // K reads done; safe to overwrite KVs with V

    // stage V tile, XOR-swizzled 8-blocks: col_block ^= (row>>3)<<3
#pragma unroll
    for (int it = 0; it < 8; ++it) {
      int idx = t + it * 256;
      int row = idx >> 4, c8 = (idx & 15) * 8;
      int c8s = c8 ^ (((row >> 3) & 15) << 3);
      *reinterpret_cast<short8*>(&KVs[row][c8s]) =
          *reinterpret_cast<const short8*>(&vptr[(size_t)(t0 + row) * Dn + c8]);
    }

    // epilogue: p = exp(score)*invl*Wepi -> global attn (f32) + Ps (bf16)
#pragma unroll
    for (int mf = 0; mf < 4; ++mf)
#pragma unroll
      for (int j = 0; j < 4; ++j) {
        const int row = mf * 16 + g * 4 + j;
        const float iv = invl[row];
        const size_t roff = (size_t)(s0 + row) * Sn + t0;
#pragma unroll
        for (int nf = 0; nf < 2; ++nf) {
          const int col = w * 32 + nf * 16 + i;
          float p = __expf(acc[mf][nf][j] * scale) * iv;
          float pf = p * Wepi[roff + col];
          attn_bh[roff + col] = pf;
          Ps[row][col] = f2bf(pf);
        }
      }
    __syncthreads();  // V staged + Ps written

    // PV accumulate
#pragma unroll
    for (int ks = 0; ks < 4; ++ks) {
      short8 pa[4], bv[2];
#pragma unroll
      for (int mf = 0; mf < 4; ++mf)
        pa[mf] = *reinterpret_cast<const short8*>(&Ps[mf * 16 + i][ks * 32 + g * 8]);
#pragma unroll
      for (int nf = 0; nf < 2; ++nf) {
        const int d0 = w * 32 + nf * 16 + i;
        const int kb = ks * 4 + g;                 // row>>3 of the 8 k-rows
        const int csw = d0 ^ ((kb & 15) << 3);     // undo staging swizzle
#pragma unroll
        for (int jj = 0; jj < 8; ++jj)
          bv[nf][jj] = (short)KVs[kb * 8 + jj][csw];
      }
#pragma unroll
      for (int mf = 0; mf < 4; ++mf)
#pragma unroll
        for (int nf = 0; nf < 2; ++nf)
          pv[mf][nf] = __builtin_amdgcn_mfma_f32_16x16x32_bf16(pa[mf], bv[nf], pv[mf][nf], 0, 0, 0);
    }
  }

  // effect = pv + bo
  const int b = bh >> 2, h = bh & 3;
#pragma unroll
  for (int mf = 0; mf < 4; ++mf)
#pragma unroll
    for (int j = 0; j < 4; ++j) {
      const int row = mf * 16 + g * 4 + j;
      const float bias = bo[s0 + row];
#pragma unroll
      for (int nf = 0; nf < 2; ++nf) {
        const int d = w * 32 + nf * 16 + i;
        effect[(size_t)(b * Sn + s0 + row) * En + h * Dn + d] = pv[mf][nf][j] + bias;
      }
    }
}

// ---------------------------------------------------------------------------
extern "C" void kernel_launch(void* const* d_in, const int* in_sizes, int n_in,
                              void* d_out, int out_size, void* d_ws, size_t ws_size,
                              hipStream_t stream) {
  const float* x    = (const float*)d_in[0];
  const float* Wq   = (const float*)d_in[1];
  const float* Wk   = (const float*)d_in[2];
  const float* Wv   = (const float*)d_in[3];
  const float* Wepi = (const float*)d_in[4];
  const float* bq   = (const float*)d_in[5];
  const float* bk   = (const float*)d_in[6];
  const float* bv   = (const float*)d_in[7];
  const float* bo   = (const float*)d_in[8];

  float* effect = (float*)d_out;
  float* attn = effect + (size_t)Bn * Sn * En;   // attn region of d_out
  unsigned short* qkv = (unsigned short*)d_ws;   // q|k|v bf16, 3 * 16.78 MB

  qkv_kernel<<<dim3(Mqkv / 128, En / 128, 3), 256, 0, stream>>>(x, Wq, Wk, Wv, bq, bk, bv, qkv);
  fused_attn_kernel<<<dim3(Sn / 64, BHn), 256, 0, stream>>>(qkv, Wepi, bo, attn, effect);
}